// Round 17
// baseline (1935.033 us; speedup 1.0000x reference)
//
#include <hip/hip_runtime.h>
#include <math.h>

// VQ-VAE quantizer: N=16384 pixels, D=256, K=8192 codes.
// d_out (float32): [0]=loss, [1..]=z_q_x, [4194305]=perplexity, [4194306..]=idx.
//
// r17: MFMA candidate-prune. Approx distances via fp16-split MFMA GEMM
// (hard error bound eps << tau), then EXACT fp32-chain eval (verified r3-r16
// semantics) only for codes within min+tau. Lexicographic u64 atomicMin
// reproduces np.argmin first-min exactly.

typedef _Float16 f16x8 __attribute__((ext_vector_type(8)));
typedef float f32x4 __attribute__((ext_vector_type(4)));

#define K_EMB 8192
#define D_EMB 256
#define NPIX  16384
#define NDTOT 4194304

#define OUT_LOSS 0
#define OUT_ZQ   1
#define OUT_PERP 4194305
#define OUT_IDX  4194306

// ws: [0]sse f32; [256]hist int[8192]; [33024]se2 f32[8192];
// [65792]sx2 f32[16384]; [131328]minb u32[16384]; [196864]packed u64[16384]
#define WS_HIST_OFF   256
#define WS_SE2_OFF    33024
#define WS_SX2_OFF    65792
#define WS_MINB_OFF   131328
#define WS_PACKED_OFF 196864

#define TAU 2.5e-4f   // >= grid(3.05e-5) + 4*eps(2.6e-5) + 2*round(1.5e-5) + slack

// GEMM geometry: block = 64 px x 128 codes, K' = 512 (eh' then el' halves).
#define BM 64
#define BN 128
#define ECH 72                     // E row fp16 (64 k' + 8 pad)
#define EBUF (128 * ECH)           // 9216 fp16 per buffer
#define XH_OFF (2 * EBUF)          // 18432 fp16
#define XROW 264                   // Xh row fp16 (256 + 8 pad)
#define SMEM_BYTES ((XH_OFF + 64 * XROW) * 2)   // 70656 B

// ---------------------------------------------------------------------------
// sx2[n] = numpy-pairwise sum of x[n][d]^2 (verified r3+).
__global__ void sx2_kernel(const float* __restrict__ z,
                           float* __restrict__ sx2) {
#pragma clang fp contract(off)
    int n = blockIdx.x * 256 + threadIdx.x;
    int b = n >> 10, hw = n & 1023;
    const float* zb = z + (size_t)b * (D_EMB * 1024) + hw;
    float half[2];
#pragma unroll
    for (int h = 0; h < 2; ++h) {
        float r[8];
#pragma unroll
        for (int j = 0; j < 8; ++j) {
            float v = zb[(size_t)(h * 128 + j) * 1024];
            r[j] = v * v;
        }
        for (int i = 8; i < 128; i += 8)
#pragma unroll
            for (int j = 0; j < 8; ++j) {
                float v = zb[(size_t)(h * 128 + i + j) * 1024];
                float sq = v * v;
                r[j] = r[j] + sq;
            }
        half[h] = ((r[0] + r[1]) + (r[2] + r[3]))
                + ((r[4] + r[5]) + (r[6] + r[7]));
    }
    sx2[n] = half[0] + half[1];
}

// ---------------------------------------------------------------------------
// se2[k] = numpy-pairwise sum of emb[k][d]^2 (verified r3+).
__global__ void se2_kernel(const float* __restrict__ emb,
                           float* __restrict__ se2) {
#pragma clang fp contract(off)
    int k = blockIdx.x * 256 + threadIdx.x;
    const float* e = emb + (size_t)k * D_EMB;
    float half[2];
#pragma unroll
    for (int h = 0; h < 2; ++h) {
        float r[8];
#pragma unroll
        for (int j = 0; j < 8; ++j) {
            float v = e[h * 128 + j];
            r[j] = v * v;
        }
        for (int i = 8; i < 128; i += 8)
#pragma unroll
            for (int j = 0; j < 8; ++j) {
                float v = e[h * 128 + i + j];
                float sq = v * v;
                r[j] = r[j] + sq;
            }
        half[h] = ((r[0] + r[1]) + (r[2] + r[3]))
                + ((r[4] + r[5]) + (r[6] + r[7]));
    }
    se2[k] = half[0] + half[1];
}

// ---------------------------------------------------------------------------
static __device__ __forceinline__ float f4c(float4 q, int j) {
    return (j == 0) ? q.x : (j == 1) ? q.y : (j == 2) ? q.z : q.w;
}

// MFMA approx GEMM + candidate prune + inline exact eval.
// 256 thr = 4 waves (2x2): wave row wr (32 px), col wc (64 codes).
// mfma_f32_16x16x32_f16; A = xh (16px x 32k'), B = e' (32k' x 16codes).
// A-frag: lane holds A[l&15][8*(l>>4)+j]; B-frag: B[8*(l>>4)+j][l&15];
// D: row=(l>>4)*4+j, col=l&15  [m89-verified C/D layout].
__global__ __launch_bounds__(256, 2) void mfma_kernel(
        const float* __restrict__ z, const float* __restrict__ emb,
        const float* __restrict__ sx2, const float* __restrict__ se2,
        unsigned int* __restrict__ minb,
        unsigned long long* __restrict__ packed) {
#pragma clang fp contract(off)
    extern __shared__ _Float16 sm[];
    _Float16* Ebuf = sm;               // [2][128][ECH]
    _Float16* Xh   = sm + XH_OFF;      // [64][XROW]
    float*    Xtmp = (float*)sm;       // [128][68] f32, init scratch

    const int t    = threadIdx.x;
    const int lane = t & 63;
    const int w    = t >> 6;
    const int wr   = w >> 1, wc = w & 1;
    const int mt   = blockIdx.x & 255;     // m fast -> n-tile-major schedule
    const int nt   = blockIdx.x >> 8;
    const int n0   = mt * BM;
    const int kb   = nt * BN;
    const int b    = n0 >> 10, hw0 = n0 & 1023;
    const float* zb = z + (size_t)b * 262144 + hw0;

    // ---- X: coalesced f32 [d][px] -> transpose+cvt -> fp16 Xh [px][d] ----
#pragma unroll
    for (int ph = 0; ph < 2; ++ph) {
        const int d0 = ph * 128;
        {
            int px = t & 63, dg = t >> 6;
#pragma unroll
            for (int m2 = 0; m2 < 32; ++m2) {
                int d = dg + 4 * m2;
                Xtmp[d * 68 + px] = zb[(size_t)(d0 + d) * 1024 + px];
            }
        }
        __syncthreads();
        {
            int px = t & 63, j0 = t >> 6;
#pragma unroll
            for (int m2 = 0; m2 < 4; ++m2) {
                int j = j0 + 4 * m2;          // 16 d-blocks of 8
                f16x8 v;
#pragma unroll
                for (int i = 0; i < 8; ++i)
                    v[i] = (_Float16)Xtmp[(8 * j + i) * 68 + px];
                *(f16x8*)&Xh[px * XROW + d0 + 8 * j] = v;
            }
        }
        __syncthreads();
    }

    // E staging: thread -> (code, half-row); 32 f32 -> fp16 (scaled split)
    const int scode = t >> 1, spart = t & 1;
    const float* esrc = emb + (size_t)(kb + scode) * 256 + 32 * spart;

    // prologue: chunk 0 (dbase 0, eh' half) into buffer 0
    {
        float4 v4[8];
#pragma unroll
        for (int i = 0; i < 8; ++i)
            v4[i] = *(const float4*)(esrc + 4 * i);
        _Float16* dst = Ebuf + scode * ECH + 32 * spart;
#pragma unroll
        for (int q8 = 0; q8 < 4; ++q8) {
            f16x8 o;
#pragma unroll
            for (int i2 = 0; i2 < 8; ++i2) {
                int fi = 8 * q8 + i2;
                float s = f4c(v4[fi >> 2], fi & 3) * 8192.0f;
                o[i2] = (_Float16)s;
            }
            *(f16x8*)(dst + 8 * q8) = o;
        }
    }
    __syncthreads();

    f32x4 acc[2][4];
#pragma unroll
    for (int rt = 0; rt < 2; ++rt)
#pragma unroll
        for (int ct = 0; ct < 4; ++ct)
            acc[rt][ct] = (f32x4){0.0f, 0.0f, 0.0f, 0.0f};

    const int arow0 = (32 * wr + (lane & 15)) * XROW;
    const int ag    = 8 * (lane >> 4);
    int br[4];
#pragma unroll
    for (int ct = 0; ct < 4; ++ct)
        br[ct] = (64 * wc + 16 * ct + (lane & 15)) * ECH;

    // K' = 512: chunks 0-3 = eh' (d 0..255), 4-7 = el' (same d again)
    for (int c = 0; c < 8; ++c) {
        const int buf = c & 1;
        float4 v4[8];
        if (c < 7) {
            const float* src = esrc + 64 * ((c + 1) & 3);
#pragma unroll
            for (int i = 0; i < 8; ++i)
                v4[i] = *(const float4*)(src + 4 * i);
        }
        const _Float16* Ec = Ebuf + buf * EBUF;
        const int dbase = 64 * (c & 3);
#pragma unroll
        for (int ks = 0; ks < 2; ++ks) {
            const int xoff = dbase + ks * 32 + ag;
            f16x8 A0 = *(const f16x8*)&Xh[arow0 + xoff];
            f16x8 A1 = *(const f16x8*)&Xh[arow0 + 16 * XROW + xoff];
            const int eoff = ks * 32 + ag;
#pragma unroll
            for (int ct = 0; ct < 4; ++ct) {
                f16x8 B = *(const f16x8*)&Ec[br[ct] + eoff];
                acc[0][ct] = __builtin_amdgcn_mfma_f32_16x16x32_f16(
                    A0, B, acc[0][ct], 0, 0, 0);
                acc[1][ct] = __builtin_amdgcn_mfma_f32_16x16x32_f16(
                    A1, B, acc[1][ct], 0, 0, 0);
            }
        }
        __syncthreads();
        if (c < 7) {
            const bool elh = ((c + 1) >> 2) != 0;
            _Float16* dst = Ebuf + (buf ^ 1) * EBUF + scode * ECH + 32 * spart;
#pragma unroll
            for (int q8 = 0; q8 < 4; ++q8) {
                f16x8 o;
#pragma unroll
                for (int i2 = 0; i2 < 8; ++i2) {
                    int fi = 8 * q8 + i2;
                    float s = f4c(v4[fi >> 2], fi & 3) * 8192.0f;
                    _Float16 eh = (_Float16)s;
                    o[i2] = elh ? (_Float16)(s - (float)eh) : eh;
                }
                *(f16x8*)(dst + 8 * q8) = o;
            }
        }
        __syncthreads();
    }

    // ---- epilogue: dist, block-min, prune, exact eval ----
    const int lg = lane >> 4;
    const int lc = lane & 15;
#pragma unroll
    for (int rt = 0; rt < 2; ++rt) {
#pragma unroll
        for (int j = 0; j < 4; ++j) {
            const int px = 32 * wr + 16 * rt + 4 * lg + j;
            const int n  = n0 + px;
            const float sx = sx2[n];
            float dv[4];
            float mn = 3.0e38f;
#pragma unroll
            for (int ct = 0; ct < 4; ++ct) {
                dv[ct] = sx - acc[rt][ct][j] * 2.44140625e-4f;  // 2^-12 exact
                mn = fminf(mn, dv[ct]);
            }
#pragma unroll
            for (int msk = 1; msk <= 8; msk <<= 1)
                mn = fminf(mn, __shfl_xor(mn, msk, 64));
            if (lc == 0) atomicMin(&minb[n], __float_as_uint(mn));
            float mb  = __uint_as_float(minb[n]);   // stale-safe upper bound
            float thr = fminf(mb, mn) + TAU;
#pragma unroll
            for (int ct = 0; ct < 4; ++ct) {
                if (dv[ct] <= thr) {
                    const int k = kb + 64 * wc + 16 * ct + lc;
                    const float* xp = z + (size_t)(n >> 10) * 262144 + (n & 1023);
                    const float* ep = emb + (size_t)k * 256;
                    float s = 0.0f;
                    for (int d = 0; d < 256; ++d)   // np/BLAS chain, d ascending
                        s = __builtin_fmaf(xp[(size_t)d * 1024], ep[d], s);
                    float A2 = sx + se2[k];
                    float g  = A2 - 2.0f * s;
                    unsigned long long key =
                        ((unsigned long long)__float_as_uint(g) << 32)
                        | (unsigned)k;
                    atomicMin(&packed[n], key);
                }
            }
        }
    }
}

// ---------------------------------------------------------------------------
__global__ void writeidx_kernel(const unsigned long long* __restrict__ packed,
                                float* __restrict__ out_idx,
                                int* __restrict__ hist) {
    int n = blockIdx.x * 256 + threadIdx.x;
    unsigned k = (unsigned)packed[n] & 8191u;
    out_idx[n] = (float)k;
    atomicAdd(&hist[k], 1);
}

// ---------------------------------------------------------------------------
__global__ void quantize_kernel(const float* __restrict__ z,
                                const float* __restrict__ emb,
                                const float* __restrict__ idxf,
                                float* __restrict__ zq,
                                float* __restrict__ sse) {
    int o = (blockIdx.x * 256 + threadIdx.x) * 4;
    int hw = o & 1023;
    int c  = (o >> 10) & 255;
    int b  = o >> 18;
    int nbase = b * 1024 + hw;
    float4 x = *(const float4*)(z + o);
    float q0 = emb[(size_t)((int)idxf[nbase + 0]) * D_EMB + c];
    float q1 = emb[(size_t)((int)idxf[nbase + 1]) * D_EMB + c];
    float q2 = emb[(size_t)((int)idxf[nbase + 2]) * D_EMB + c];
    float q3 = emb[(size_t)((int)idxf[nbase + 3]) * D_EMB + c];
    float4 q = make_float4(q0, q1, q2, q3);
    *(float4*)(zq + o) = q;
    float d0 = q.x - x.x, d1 = q.y - x.y, d2 = q.z - x.z, d3 = q.w - x.w;
    float s = d0 * d0 + d1 * d1 + d2 * d2 + d3 * d3;
#pragma unroll
    for (int m = 1; m < 64; m <<= 1) s += __shfl_xor(s, m, 64);
    __shared__ float red[4];
    int lane = threadIdx.x & 63, wv = threadIdx.x >> 6;
    if (lane == 0) red[wv] = s;
    __syncthreads();
    if (threadIdx.x == 0)
        atomicAdd(sse, red[0] + red[1] + red[2] + red[3]);
}

// ---------------------------------------------------------------------------
__global__ void finalize_kernel(const int* __restrict__ hist,
                                const float* __restrict__ sse,
                                float* __restrict__ out) {
    float s = 0.0f;
    for (int i = threadIdx.x; i < K_EMB; i += 256) {
        float p = (float)hist[i] * (1.0f / (float)NPIX);
        s += p * logf(p + 1e-10f);
    }
#pragma unroll
    for (int m = 1; m < 64; m <<= 1) s += __shfl_xor(s, m, 64);
    __shared__ float red[4];
    int lane = threadIdx.x & 63, wv = threadIdx.x >> 6;
    if (lane == 0) red[wv] = s;
    __syncthreads();
    if (threadIdx.x == 0) {
        float H = -(red[0] + red[1] + red[2] + red[3]);
        out[OUT_PERP] = expf(H);
        out[OUT_LOSS] = 1.25f * sse[0] / (float)NDTOT;
    }
}

// ---------------------------------------------------------------------------
extern "C" void kernel_launch(void* const* d_in, const int* in_sizes, int n_in,
                              void* d_out, int out_size, void* d_ws, size_t ws_size,
                              hipStream_t stream) {
    const float* z   = (const float*)d_in[0];   // [16,256,32,32]
    const float* emb = (const float*)d_in[1];   // [8192,256]
    float* out = (float*)d_out;
    char*  ws  = (char*)d_ws;
    float*              sse    = (float*)(ws);
    int*                hist   = (int*)(ws + WS_HIST_OFF);
    float*              se2    = (float*)(ws + WS_SE2_OFF);
    float*              sx2    = (float*)(ws + WS_SX2_OFF);
    unsigned int*       minb   = (unsigned int*)(ws + WS_MINB_OFF);
    unsigned long long* packed = (unsigned long long*)(ws + WS_PACKED_OFF);

    static int attr_done = 0;
    if (!attr_done) {
        (void)hipFuncSetAttribute((const void*)mfma_kernel,
                                  hipFuncAttributeMaxDynamicSharedMemorySize,
                                  SMEM_BYTES);
        attr_done = 1;
    }

    // zero sse+hist; init minb/packed to large positive pattern (0x7F7F...)
    hipMemsetAsync(ws, 0, WS_SE2_OFF, stream);
    hipMemsetAsync(ws + WS_MINB_OFF, 0x7F, 65536 + 131072, stream);

    sx2_kernel<<<NPIX / 256, 256, 0, stream>>>(z, sx2);
    se2_kernel<<<K_EMB / 256, 256, 0, stream>>>(emb, se2);
    mfma_kernel<<<(NPIX / BM) * (K_EMB / BN), 256, SMEM_BYTES, stream>>>(
        z, emb, sx2, se2, minb, packed);
    writeidx_kernel<<<NPIX / 256, 256, 0, stream>>>(packed, out + OUT_IDX, hist);
    quantize_kernel<<<NDTOT / (256 * 4), 256, 0, stream>>>(
        z, emb, out + OUT_IDX, out + OUT_ZQ, sse);
    finalize_kernel<<<1, 256, 0, stream>>>(hist, sse, out);
}

// Round 18
// 523.954 us; speedup vs baseline: 3.6931x; 3.6931x over previous
//
#include <hip/hip_runtime.h>
#include <math.h>

// VQ-VAE quantizer: N=16384 pixels, D=256, K=8192 codes.
// d_out (float32): [0]=loss, [1..]=z_q_x, [4194305]=perplexity, [4194306..]=idx.
//
// r18: restructured r17 (verified-correct MFMA candidate-prune). One block per
// 64-px tile loops all 8192 codes: X transposed once, E fp32 read once per
// code-tile (both fp16 halves converted together), running prefix-min in regs,
// candidates batched through an LDS queue, exact fp32-chain eval (verified
// r3-r17 np semantics) wave-parallel at block end, block-local u64 atomicMin
// argmin. No cross-block atomics, no ws growth.

typedef _Float16 f16x8 __attribute__((ext_vector_type(8)));
typedef float f32x4 __attribute__((ext_vector_type(4)));

#define K_EMB 8192
#define D_EMB 256
#define NPIX  16384
#define NDTOT 4194304

#define OUT_LOSS 0
#define OUT_ZQ   1
#define OUT_PERP 4194305
#define OUT_IDX  4194306

// ws: [0]sse f32; [256]hist int[8192]; [33024]se2 f32[8192]; [65792]sx2 f32[16384]
#define WS_HIST_OFF 256
#define WS_SE2_OFF  33024
#define WS_SX2_OFF  65792

#define TAU 2.5e-4f     // >= 2*eps(fp16-split approx) + fp32 grid + slack (r17-verified)

// geometry: block = 64 px, loops 64 code-tiles of 128; schunk = 128c x 64d.
#define TN 64
#define NSTEP 256              // 64 nt x 4 schunks
#define ECROW 72               // padded fp16 row (64 + 8): conflict-free frags
#define HPLANE (128 * ECROW)   // 9216 fp16 per half-plane
#define EBUFH (2 * HPLANE)     // eh + el planes per buffer
#define XROW 264               // padded fp16 row (256 + 8)
#define QCAP 2048

// LDS layout (bytes)
#define LDS_EB    0                       // 2 x EBUFH fp16 = 73728
#define LDS_XH    73728                   // 64*XROW fp16 = 33792
#define LDS_PXMIN 107520                  // 64 x u64 = 512
#define LDS_QCNT  108032                  // int
#define LDS_QUEUE 108048                  // QCAP x u32 = 8192
#define SMEM_BYTES 116240

// ---------------------------------------------------------------------------
__global__ void sx2_kernel(const float* __restrict__ z,
                           float* __restrict__ sx2) {
#pragma clang fp contract(off)
    int n = blockIdx.x * 256 + threadIdx.x;
    int b = n >> 10, hw = n & 1023;
    const float* zb = z + (size_t)b * (D_EMB * 1024) + hw;
    float half[2];
#pragma unroll
    for (int h = 0; h < 2; ++h) {
        float r[8];
#pragma unroll
        for (int j = 0; j < 8; ++j) {
            float v = zb[(size_t)(h * 128 + j) * 1024];
            r[j] = v * v;
        }
        for (int i = 8; i < 128; i += 8)
#pragma unroll
            for (int j = 0; j < 8; ++j) {
                float v = zb[(size_t)(h * 128 + i + j) * 1024];
                float sq = v * v;
                r[j] = r[j] + sq;
            }
        half[h] = ((r[0] + r[1]) + (r[2] + r[3]))
                + ((r[4] + r[5]) + (r[6] + r[7]));
    }
    sx2[n] = half[0] + half[1];
}

// ---------------------------------------------------------------------------
__global__ void se2_kernel(const float* __restrict__ emb,
                           float* __restrict__ se2) {
#pragma clang fp contract(off)
    int k = blockIdx.x * 256 + threadIdx.x;
    const float* e = emb + (size_t)k * D_EMB;
    float half[2];
#pragma unroll
    for (int h = 0; h < 2; ++h) {
        float r[8];
#pragma unroll
        for (int j = 0; j < 8; ++j) {
            float v = e[h * 128 + j];
            r[j] = v * v;
        }
        for (int i = 8; i < 128; i += 8)
#pragma unroll
            for (int j = 0; j < 8; ++j) {
                float v = e[h * 128 + i + j];
                float sq = v * v;
                r[j] = r[j] + sq;
            }
        half[h] = ((r[0] + r[1]) + (r[2] + r[3]))
                + ((r[4] + r[5]) + (r[6] + r[7]));
    }
    se2[k] = half[0] + half[1];
}

// ---------------------------------------------------------------------------
static __device__ __forceinline__ float f4c(float4 q, int j) {
    return (j == 0) ? q.x : (j == 1) ? q.y : (j == 2) ? q.z : q.w;
}

// exact np-semantics distance (verified r3-r17): sequential d=0..255 fp32 FMA
// chain; g = f32(sx2+se2) - 2*S.
static __device__ __forceinline__ float exact_g(
        const float* __restrict__ z, const float* __restrict__ emb,
        const float* __restrict__ se2, const float* __restrict__ sx2,
        int n, int k) {
#pragma clang fp contract(off)
    const float* xp = z + (size_t)(n >> 10) * 262144 + (n & 1023);
    const float* ep = emb + (size_t)k * 256;
    float s = 0.0f;
    for (int d = 0; d < 256; ++d)
        s = __builtin_fmaf(xp[(size_t)d * 1024], ep[d], s);
    float A = sx2[n] + se2[k];
    return A - 2.0f * s;
}

// ---------------------------------------------------------------------------
// MFMA prune kernel. Grid 256 (one 64-px tile each), 512 thr = 8 waves
// (wr 0..3: 16-px tiles, wc 0..1: 64-code halves). Loops 64 code-tiles.
// mfma_f32_16x16x32_f16; A-frag lane: A[l&15][8*(l>>4)+j]; B-frag:
// B[8*(l>>4)+j][l&15]; D: row=(l>>4)*4+j, col=l&15 (r17-verified).
__global__ __launch_bounds__(512, 1) void mfma_kernel(
        const float* __restrict__ z, const float* __restrict__ emb,
        const float* __restrict__ sx2, const float* __restrict__ se2,
        float* __restrict__ out_idx, int* __restrict__ hist) {
#pragma clang fp contract(off)
    extern __shared__ char sm[];
    _Float16* EB   = (_Float16*)(sm + LDS_EB);     // [2][2][128][ECROW]
    _Float16* Xh   = (_Float16*)(sm + LDS_XH);     // [64][XROW]
    unsigned long long* pxmin = (unsigned long long*)(sm + LDS_PXMIN);
    int*      qcnt  = (int*)(sm + LDS_QCNT);
    unsigned* queue = (unsigned*)(sm + LDS_QUEUE);

    const int t    = threadIdx.x;
    const int lane = t & 63;
    const int w    = t >> 6;
    const int wr   = w >> 1, wc = w & 1;
    const int lc   = lane & 15;
    const int lg   = lane >> 4;
    const int n0   = blockIdx.x * TN;
    const int b    = n0 >> 10, hw0 = n0 & 1023;
    const float* zb = z + (size_t)b * 262144 + hw0;

    if (t < 64) pxmin[t] = ~0ull;
    if (t == 0) *qcnt = 0;

    // ---- stage X once: [d][px] f32 -> transpose+cvt -> Xh [px][264] f16 ----
    {
        float* Xtmp = (float*)(sm + LDS_EB);       // 64d x 68px f32 slab
#pragma unroll
        for (int slab = 0; slab < 4; ++slab) {
            {
                int px = t & 63, dr = t >> 6;
#pragma unroll
                for (int r = 0; r < 8; ++r) {
                    int dl = dr * 8 + r;
                    Xtmp[dl * 68 + px] = zb[(size_t)(slab * 64 + dl) * 1024 + px];
                }
            }
            __syncthreads();
            {
                int px = t & 63, g = t >> 6;
                f16x8 v;
#pragma unroll
                for (int i = 0; i < 8; ++i)
                    v[i] = (_Float16)Xtmp[(g * 8 + i) * 68 + px];
                *(f16x8*)&Xh[px * XROW + slab * 64 + g * 8] = v;
            }
            __syncthreads();
        }
    }

    // E staging map: thread -> code = t>>2 (0..127), q = t&3 (16-d chunk).
    // Reads 64B fp32 (coalesced 256B/code), writes 2 granules to each half.
    const int scode = t >> 2, sq = t & 3;

    // prologue: schunk 0 (nt=0, d0=0) into buffer 0
    {
        const float* src = emb + (size_t)scode * 256 + 16 * sq;
        float4 v4[4];
#pragma unroll
        for (int p = 0; p < 4; ++p) v4[p] = *(const float4*)(src + 4 * p);
        _Float16* eh = EB + scode * ECROW + 16 * sq;
        _Float16* el = eh + HPLANE;
#pragma unroll
        for (int g2 = 0; g2 < 2; ++g2) {
            f16x8 oh, ol;
#pragma unroll
            for (int i = 0; i < 8; ++i) {
                float f = f4c(v4[(8 * g2 + i) >> 2], (8 * g2 + i) & 3) * 8192.0f;
                _Float16 h = (_Float16)f;
                oh[i] = h;
                ol[i] = (_Float16)(f - (float)h);
            }
            *(f16x8*)(eh + 8 * g2) = oh;
            *(f16x8*)(el + 8 * g2) = ol;
        }
    }
    __syncthreads();

    float sxr[4];
#pragma unroll
    for (int j = 0; j < 4; ++j)
        sxr[j] = sx2[n0 + 16 * wr + 4 * lg + j];

    float minv[4];
#pragma unroll
    for (int j = 0; j < 4; ++j) minv[j] = 3.0e38f;

    f32x4 acc[4];
#pragma unroll
    for (int ct = 0; ct < 4; ++ct) acc[ct] = (f32x4){0.f, 0.f, 0.f, 0.f};

    const int arow = (16 * wr + lc) * XROW;
    const int ag   = 8 * lg;
    int brow[4];
#pragma unroll
    for (int ct = 0; ct < 4; ++ct)
        brow[ct] = (64 * wc + 16 * ct + lc) * ECROW;

    for (int s = 0; s < NSTEP; ++s) {
        const bool pf = (s + 1 < NSTEP);

        // T14: prefetch next schunk's fp32 E into regs
        float4 v4[4];
        if (pf) {
            const int nt1 = (s + 1) >> 2, d01 = ((s + 1) & 3) * 64;
            const float* src = emb + (size_t)(nt1 * 128 + scode) * 256
                             + d01 + 16 * sq;
#pragma unroll
            for (int p = 0; p < 4; ++p) v4[p] = *(const float4*)(src + 4 * p);
        }

        // compute: 16 MFMA / wave (2 ks x 2 halves x 4 ct)
        const _Float16* Ec = EB + (s & 1) * EBUFH;
        const int d0 = (s & 3) * 64;
#pragma unroll
        for (int ks = 0; ks < 2; ++ks) {
            f16x8 A = *(const f16x8*)&Xh[arow + d0 + ks * 32 + ag];
#pragma unroll
            for (int h = 0; h < 2; ++h) {
                const _Float16* Ep = Ec + h * HPLANE;
#pragma unroll
                for (int ct = 0; ct < 4; ++ct) {
                    f16x8 B = *(const f16x8*)&Ep[brow[ct] + ks * 32 + ag];
                    acc[ct] = __builtin_amdgcn_mfma_f32_16x16x32_f16(
                        A, B, acc[ct], 0, 0, 0);
                }
            }
        }

        // end of code-tile: prune epilogue
        if ((s & 3) == 3) {
            const int nt = s >> 2;
            const int kb = nt * 128 + 64 * wc;
#pragma unroll
            for (int j = 0; j < 4; ++j) {
                float dv[4];
                float mn = 3.0e38f;
#pragma unroll
                for (int ct = 0; ct < 4; ++ct) {
                    dv[ct] = sxr[j] - acc[ct][j] * 2.44140625e-4f;  // 2^-12
                    mn = fminf(mn, dv[ct]);
                }
#pragma unroll
                for (int msk = 1; msk <= 8; msk <<= 1)
                    mn = fminf(mn, __shfl_xor(mn, msk, 64));
                minv[j] = fminf(minv[j], mn);
                float thr = minv[j] + TAU;
                const int px = 16 * wr + 4 * lg + j;
#pragma unroll
                for (int ct = 0; ct < 4; ++ct) {
                    if (dv[ct] <= thr) {
                        int k = kb + 16 * ct + lc;
                        int qi = atomicAdd(qcnt, 1);
                        if (qi < QCAP) {
                            queue[qi] = ((unsigned)px << 13) | (unsigned)k;
                        } else {   // correct slow fallback (never expected)
                            float g = exact_g(z, emb, se2, sx2, n0 + px, k);
                            unsigned long long key =
                                ((unsigned long long)__float_as_uint(g) << 32)
                                | (unsigned)k;
                            atomicMin(&pxmin[px], key);
                        }
                    }
                }
            }
#pragma unroll
            for (int ct = 0; ct < 4; ++ct) acc[ct] = (f32x4){0.f, 0.f, 0.f, 0.f};
        }

        __syncthreads();
        if (pf) {   // convert + write next schunk (both halves)
            _Float16* eh = EB + ((s + 1) & 1) * EBUFH + scode * ECROW + 16 * sq;
            _Float16* el = eh + HPLANE;
#pragma unroll
            for (int g2 = 0; g2 < 2; ++g2) {
                f16x8 oh, ol;
#pragma unroll
                for (int i = 0; i < 8; ++i) {
                    float f = f4c(v4[(8 * g2 + i) >> 2], (8 * g2 + i) & 3)
                            * 8192.0f;
                    _Float16 h = (_Float16)f;
                    oh[i] = h;
                    ol[i] = (_Float16)(f - (float)h);
                }
                *(f16x8*)(eh + 8 * g2) = oh;
                *(f16x8*)(el + 8 * g2) = ol;
            }
        }
        __syncthreads();
    }

    // ---- batched exact eval of all candidates (wave-parallel) ----
    int qn = *qcnt;
    if (qn > QCAP) qn = QCAP;
    for (int i = t; i < qn; i += 512) {
        unsigned e = queue[i];
        int px = e >> 13, k = e & 8191;
        float g = exact_g(z, emb, se2, sx2, n0 + px, k);
        unsigned long long key =
            ((unsigned long long)__float_as_uint(g) << 32) | (unsigned)k;
        atomicMin(&pxmin[px], key);
    }
    __syncthreads();

    if (t < 64) {
        int k = (int)(pxmin[t] & 8191u);
        out_idx[n0 + t] = (float)k;
        atomicAdd(&hist[k], 1);
    }
}

// ---------------------------------------------------------------------------
__global__ void quantize_kernel(const float* __restrict__ z,
                                const float* __restrict__ emb,
                                const float* __restrict__ idxf,
                                float* __restrict__ zq,
                                float* __restrict__ sse) {
    int o = (blockIdx.x * 256 + threadIdx.x) * 4;
    int hw = o & 1023;
    int c  = (o >> 10) & 255;
    int b  = o >> 18;
    int nbase = b * 1024 + hw;
    float4 x = *(const float4*)(z + o);
    float q0 = emb[(size_t)((int)idxf[nbase + 0]) * D_EMB + c];
    float q1 = emb[(size_t)((int)idxf[nbase + 1]) * D_EMB + c];
    float q2 = emb[(size_t)((int)idxf[nbase + 2]) * D_EMB + c];
    float q3 = emb[(size_t)((int)idxf[nbase + 3]) * D_EMB + c];
    float4 q = make_float4(q0, q1, q2, q3);
    *(float4*)(zq + o) = q;
    float d0 = q.x - x.x, d1 = q.y - x.y, d2 = q.z - x.z, d3 = q.w - x.w;
    float s = d0 * d0 + d1 * d1 + d2 * d2 + d3 * d3;
#pragma unroll
    for (int m = 1; m < 64; m <<= 1) s += __shfl_xor(s, m, 64);
    __shared__ float red[4];
    int lane = threadIdx.x & 63, wv = threadIdx.x >> 6;
    if (lane == 0) red[wv] = s;
    __syncthreads();
    if (threadIdx.x == 0)
        atomicAdd(sse, red[0] + red[1] + red[2] + red[3]);
}

// ---------------------------------------------------------------------------
__global__ void finalize_kernel(const int* __restrict__ hist,
                                const float* __restrict__ sse,
                                float* __restrict__ out) {
    float s = 0.0f;
    for (int i = threadIdx.x; i < K_EMB; i += 256) {
        float p = (float)hist[i] * (1.0f / (float)NPIX);
        s += p * logf(p + 1e-10f);
    }
#pragma unroll
    for (int m = 1; m < 64; m <<= 1) s += __shfl_xor(s, m, 64);
    __shared__ float red[4];
    int lane = threadIdx.x & 63, wv = threadIdx.x >> 6;
    if (lane == 0) red[wv] = s;
    __syncthreads();
    if (threadIdx.x == 0) {
        float H = -(red[0] + red[1] + red[2] + red[3]);
        out[OUT_PERP] = expf(H);
        out[OUT_LOSS] = 1.25f * sse[0] / (float)NDTOT;
    }
}

// ---------------------------------------------------------------------------
extern "C" void kernel_launch(void* const* d_in, const int* in_sizes, int n_in,
                              void* d_out, int out_size, void* d_ws, size_t ws_size,
                              hipStream_t stream) {
    const float* z   = (const float*)d_in[0];   // [16,256,32,32]
    const float* emb = (const float*)d_in[1];   // [8192,256]
    float* out = (float*)d_out;
    char*  ws  = (char*)d_ws;
    float* sse  = (float*)(ws);
    int*   hist = (int*)(ws + WS_HIST_OFF);
    float* se2  = (float*)(ws + WS_SE2_OFF);
    float* sx2  = (float*)(ws + WS_SX2_OFF);

    static int attr_done = 0;
    if (!attr_done) {
        (void)hipFuncSetAttribute((const void*)mfma_kernel,
                                  hipFuncAttributeMaxDynamicSharedMemorySize,
                                  SMEM_BYTES);
        attr_done = 1;
    }

    // zero sse + hist every call (graph replays don't re-poison)
    hipMemsetAsync(ws, 0, WS_SE2_OFF, stream);

    sx2_kernel<<<NPIX / 256, 256, 0, stream>>>(z, sx2);
    se2_kernel<<<K_EMB / 256, 256, 0, stream>>>(emb, se2);
    mfma_kernel<<<NPIX / TN, 512, SMEM_BYTES, stream>>>(
        z, emb, sx2, se2, out + OUT_IDX, hist);
    quantize_kernel<<<NDTOT / (256 * 4), 256, 0, stream>>>(
        z, emb, out + OUT_IDX, out + OUT_ZQ, sse);
    finalize_kernel<<<1, 256, 0, stream>>>(hist, sse, out);
}